// Round 6
// baseline (111.803 us; speedup 1.0000x reference)
//
#include <hip/hip_runtime.h>
#include <hip/hip_bf16.h>
#include <stdint.h>

#define NN    4096
#define INF_  256
#define HEADS 4
#define HID   64
#define OUTC  256
#define NEG   0.2f
#define L2E   1.44269504f

#define BI     32
#define JSPLIT 8
#define NJ     (NN / JSPLIT)

typedef short bf16x8 __attribute__((ext_vector_type(8)));
typedef float f32x4  __attribute__((ext_vector_type(4)));

// ---- float <-> order-preserving uint encoding (for atomicMax on f32) ----
__device__ __forceinline__ uint32_t ford(float x){
  uint32_t u = __float_as_uint(x);
  return (u & 0x80000000u) ? ~u : (u | 0x80000000u);
}
__device__ __forceinline__ float funord(uint32_t e){
  uint32_t u = (e & 0x80000000u) ? (e & 0x7fffffffu) : ~e;
  return __uint_as_float(u);
}
__device__ __forceinline__ ushort bf16u(float f){
  __hip_bfloat16 b = __float2bfloat16(f);
  return *reinterpret_cast<ushort*>(&b);
}

// split 8 f32 -> bf16 hi (trunc) + bf16 lo (exact residual, trunc)
__device__ __forceinline__ void split8(float4 a0, float4 a1, bf16x8& hi, bf16x8& lo){
  float av[8] = {a0.x, a0.y, a0.z, a0.w, a1.x, a1.y, a1.z, a1.w};
  ushort hu[8], lu[8];
  #pragma unroll
  for (int q = 0; q < 8; q++){
    uint32_t u = __float_as_uint(av[q]);
    hu[q] = (ushort)(u >> 16);
    float hf = __uint_as_float(u & 0xffff0000u);
    lu[q] = (ushort)(__float_as_uint(av[q] - hf) >> 16);
  }
  hi = *(bf16x8*)hu;
  lo = *(bf16x8*)lu;
}

// ---- fused prep: adjacency->bitmask pack (4/5 of blocks) + g-GEMM (1/5) ----
// interleaved 4:1 so the HBM-bound pack overlaps the latency-bound GEMM.
__launch_bounds__(256)
__global__ void k_prep(const int* __restrict__ adj, const float* __restrict__ hmat,
                       const float* __restrict__ W, const float* __restrict__ aw,
                       uint32_t* __restrict__ bm, short* __restrict__ gT,
                       float* __restrict__ slT2, float* __restrict__ srT2,
                       uint32_t* __restrict__ srmax2){
  __shared__ float red[64][69];   // gemm: [lane][wave*17 + val]; pack reuses as ushort buf
  int bx = blockIdx.x, t = threadIdx.x;
  int role = bx % 5;

  if (role < 4){
    // ---- pack: one adjacency row -> 128 bitmask words ----
    int i = (bx/5)*4 + role;
    ushort* sh = (ushort*)red;
    const int* row = adj + (size_t)i*NN + t*16;
    uint32_t b = 0;
    #pragma unroll
    for (int u = 0; u < 4; u++){
      int4 v = *(const int4*)(row + u*4);
      b |= (v.x ? 1u : 0u) << (u*4 + 0);
      b |= (v.y ? 1u : 0u) << (u*4 + 1);
      b |= (v.z ? 1u : 0u) << (u*4 + 2);
      b |= (v.w ? 1u : 0u) << (u*4 + 3);
    }
    sh[t] = (ushort)b;
    __syncthreads();
    if (t < 128)
      bm[(size_t)i*128 + t] = (uint32_t)sh[2*t] | ((uint32_t)sh[2*t + 1] << 16);
    return;
  }

  // ---- gemm: one (i-tile of 16, head); K split across 4 waves ----
  int id = bx/5;
  int i0 = (id & 255) * 16;
  int hd = id >> 8;
  int w = t >> 6, l = t & 63, lr = l & 15, lg = l >> 4;

  f32x4 acc[4] = {};
  #pragma unroll
  for (int ks = 0; ks < 2; ks++){
    int k0 = w*64 + ks*32 + lg*8;
    const float* ap_ = hmat + (size_t)(i0 + lr)*INF_ + k0;
    float4 a0 = *(const float4*)ap_;
    float4 a1 = *(const float4*)(ap_ + 4);
    bf16x8 ahi, alo;
    split8(a0, a1, ahi, alo);
    #pragma unroll
    for (int n = 0; n < 4; n++){
      const float* wp_ = W + (size_t)(hd*HID + n*16 + lr)*INF_ + k0;
      float4 b0 = *(const float4*)wp_;
      float4 b1 = *(const float4*)(wp_ + 4);
      bf16x8 bhi, blo;
      split8(b0, b1, bhi, blo);
      acc[n] = __builtin_amdgcn_mfma_f32_16x16x32_bf16(ahi, bhi, acc[n], 0, 0, 0);
      acc[n] = __builtin_amdgcn_mfma_f32_16x16x32_bf16(ahi, blo, acc[n], 0, 0, 0);
      acc[n] = __builtin_amdgcn_mfma_f32_16x16x32_bf16(alo, bhi, acc[n], 0, 0, 0);
    }
  }

  // cross-wave K reduce via LDS
  #pragma unroll
  for (int n = 0; n < 4; n++)
    #pragma unroll
    for (int r = 0; r < 4; r++)
      red[l][w*17 + n*4 + r] = acc[n][r];
  __syncthreads();

  if (w == 0){
    #pragma unroll
    for (int ww = 1; ww < 4; ww++)
      #pragma unroll
      for (int n = 0; n < 4; n++)
        #pragma unroll
        for (int r = 0; r < 4; r++)
          acc[n][r] += red[l][ww*17 + n*4 + r];

    // scores (log2e-scaled)
    float alv[4], arv[4];
    #pragma unroll
    for (int n = 0; n < 4; n++){ alv[n] = aw[n*16 + lr]; arv[n] = aw[64 + n*16 + lr]; }
    float rmax = -3.4e38f;
    #pragma unroll
    for (int r = 0; r < 4; r++){
      float slp = 0.f, srp = 0.f;
      #pragma unroll
      for (int n = 0; n < 4; n++){
        slp = fmaf(acc[n][r], alv[n], slp);
        srp = fmaf(acc[n][r], arv[n], srp);
      }
      #pragma unroll
      for (int m = 1; m < 16; m <<= 1){
        slp += __shfl_xor(slp, m, 64);
        srp += __shfl_xor(srp, m, 64);
      }
      slp *= L2E; srp *= L2E;
      if (lr == 0){
        slT2[(size_t)hd*NN + i0 + lg*4 + r] = slp;
        srT2[(size_t)hd*NN + i0 + lg*4 + r] = srp;
      }
      rmax = fmaxf(rmax, srp);
    }
    rmax = fmaxf(rmax, __shfl_xor(rmax, 16, 64));
    rmax = fmaxf(rmax, __shfl_xor(rmax, 32, 64));
    if (l == 0) atomicMax(srmax2 + hd, ford(rmax));

    // gT store: rows lg*4..+4 are consecutive -> uint2 per n, no LDS transpose
    #pragma unroll
    for (int n = 0; n < 4; n++){
      uint32_t p0 = (uint32_t)bf16u(acc[n][0]) | ((uint32_t)bf16u(acc[n][1]) << 16);
      uint32_t p1 = (uint32_t)bf16u(acc[n][2]) | ((uint32_t)bf16u(acc[n][3]) << 16);
      *(uint2*)&gT[(size_t)(hd*HID + n*16 + lr)*NN + i0 + lg*4] = make_uint2(p0, p1);
    }
  }
}

// ---- fused masked-softmax attention: 8 waves (4 heads x 2 i-halves),
//      zero LDS, zero barriers, weights built in MFMA A-frag layout ----
__launch_bounds__(512, 8)
__global__ void k_attn(const short* __restrict__ gT, const float* __restrict__ slT2,
                       const float* __restrict__ srT2, const uint32_t* __restrict__ srmax2,
                       const uint32_t* __restrict__ bm,
                       __hip_bfloat16* __restrict__ num_p, float* __restrict__ den_p){
  int t  = threadIdx.x;
  int w  = t >> 6;
  int h  = w & 3, ihalf = w >> 2;
  int l  = t & 63, lr = l & 15, lg = l >> 4;
  int i0 = blockIdx.x * BI + ihalf * 16;
  int jb = blockIdx.y * NJ;
  int js = blockIdx.y;

  float srmaxh = funord(srmax2[h]);
  float slv = slT2[(size_t)h*NN + i0 + lr];
  float xx  = slv + srmaxh;
  float msh = fmaxf(xx, NEG * xx);
  float d1  = slv - msh;             // z = d1 + sr
  float cc  = (NEG - 1.0f) * msh;    // NEG*z + cc = lrelu-neg branch - msh

  f32x4 acc[4] = {};
  float denp = 0.f;
  const float*    srh = srT2 + (size_t)h*NN + jb;
  const short*    gTh = gT + (size_t)h*HID*NN;
  const uint32_t* bmp = bm + (size_t)(i0 + lr)*128 + (jb >> 5);

  #pragma unroll
  for (int s = 0; s < 16; s++){
    uint32_t word = bmp[s] >> (lg*8);
    int kk = jb + s*32 + lg*8;
    float4 s0 = *(const float4*)(srh + s*32 + lg*8);
    float4 s1 = *(const float4*)(srh + s*32 + lg*8 + 4);
    float sr8[8] = {s0.x, s0.y, s0.z, s0.w, s1.x, s1.y, s1.z, s1.w};

    uint32_t pk[4];
    #pragma unroll
    for (int p = 0; p < 4; p++){
      float z0 = d1 + sr8[2*p];
      float z1 = d1 + sr8[2*p + 1];
      float w0 = __builtin_amdgcn_exp2f(fmaxf(z0, fmaf(NEG, z0, cc)));
      float w1 = __builtin_amdgcn_exp2f(fmaxf(z1, fmaf(NEG, z1, cc)));
      w0 = (word & (1u << (2*p)))     ? w0 : 0.f;
      w1 = (word & (1u << (2*p + 1))) ? w1 : 0.f;
      denp += w0;
      denp += w1;
      pk[p] = ((__float_as_uint(w0) + 0x8000u) >> 16) |
              ((__float_as_uint(w1) + 0x8000u) & 0xffff0000u);
    }
    bf16x8 A = *(bf16x8*)pk;

    bf16x8 B0 = *(const bf16x8*)(gTh + (size_t)(0*16 + lr)*NN + kk);
    bf16x8 B1 = *(const bf16x8*)(gTh + (size_t)(1*16 + lr)*NN + kk);
    acc[0] = __builtin_amdgcn_mfma_f32_16x16x32_bf16(A, B0, acc[0], 0, 0, 0);
    acc[1] = __builtin_amdgcn_mfma_f32_16x16x32_bf16(A, B1, acc[1], 0, 0, 0);
    bf16x8 B2 = *(const bf16x8*)(gTh + (size_t)(2*16 + lr)*NN + kk);
    bf16x8 B3 = *(const bf16x8*)(gTh + (size_t)(3*16 + lr)*NN + kk);
    acc[2] = __builtin_amdgcn_mfma_f32_16x16x32_bf16(A, B2, acc[2], 0, 0, 0);
    acc[3] = __builtin_amdgcn_mfma_f32_16x16x32_bf16(A, B3, acc[3], 0, 0, 0);
  }

  // num partials (bf16): row = i0+lg*4+r, col = h*64+n*16+lr
  #pragma unroll
  for (int n = 0; n < 4; n++)
    #pragma unroll
    for (int r = 0; r < 4; r++)
      num_p[((size_t)js*NN + i0 + lg*4 + r)*OUTC + h*HID + n*16 + lr] =
          __float2bfloat16(acc[n][r]);

  denp += __shfl_xor(denp, 16, 64);
  denp += __shfl_xor(denp, 32, 64);
  if (lg == 0)
    den_p[((size_t)js*4 + h)*NN + i0 + lr] = denp;
}

// ---- combine partials: out = sum(num)/sum(den) ----
__global__ void k_comb(const __hip_bfloat16* __restrict__ num_p,
                       const float* __restrict__ den_p, float* __restrict__ out){
  int r = blockIdx.x, c = threadIdx.x;
  int h = c >> 6;
  float s = 0.f, d = 0.f;
  #pragma unroll
  for (int js = 0; js < JSPLIT; js++)
    s += __bfloat162float(num_p[((size_t)js*NN + r)*OUTC + c]);
  #pragma unroll
  for (int js = 0; js < JSPLIT; js++)
    d += den_p[((size_t)js*4 + h)*NN + r];
  out[(size_t)r*OUTC + c] = s / d;
}

extern "C" void kernel_launch(void* const* d_in, const int* in_sizes, int n_in,
                              void* d_out, int out_size, void* d_ws, size_t ws_size,
                              hipStream_t stream){
  const float* hmat = (const float*)d_in[0];
  const int*   adj  = (const int*)d_in[1];     // int32 layout confirmed in r1
  const float* W    = (const float*)d_in[2];
  const float* aw   = (const float*)d_in[3];
  float* out = (float*)d_out;
  char*  ws  = (char*)d_ws;

  // ws layout (bytes), total ~21.6 MB
  uint32_t* srmax2 = (uint32_t*)(ws);                      // 64 B
  float*    slT2   = (float*)(ws + 1024);                  // 64 KB
  float*    srT2   = (float*)(ws + 66560);                 // 64 KB
  short*    gT     = (short*)(ws + 132096);                // 2 MB   [256][4096] bf16
  float*    den_p  = (float*)(ws + 2229248);               // 512 KB [8][4][4096]
  __hip_bfloat16* num_p = (__hip_bfloat16*)(ws + 2753536); // 16.75 MB [8][4096][256]
  uint32_t* bmask  = (uint32_t*)(ws + 19530752);           // 2 MB   [4096][128]

  hipMemsetAsync(ws, 0, 64, stream);   // srmax2 init
  hipLaunchKernelGGL(k_prep, dim3(5120), dim3(256), 0, stream,
                     adj, hmat, W, aw, bmask, gT, slT2, srT2, srmax2);
  hipLaunchKernelGGL(k_attn, dim3(NN/BI, JSPLIT), dim3(512), 0, stream,
                     gT, slT2, srT2, srmax2, bmask, num_p, den_p);
  hipLaunchKernelGGL(k_comb, dim3(NN), dim3(256), 0, stream, num_p, den_p, out);
}